// Round 6
// baseline (45.855 us; speedup 1.0000x reference)
//
#include <hip/hip_runtime.h>

// Stand-alone self-attention block, fully fused.
// x:(8,64,128,128) f32 -> out same shape. G=8, Cg=8, 3x3 window, pad 1.
//
// R6 structure: 1 block = one (b,g) x 32x16 tile x 2-channel chunk.
// 8192 blocks x 256 threads; thread = 1 row x 2 px.
// Design goal: VGPR <= 64 (occupancy cliff at 64 -> 8 waves/EU = 32/CU):
//  - xi as float2[8] (16 VGPR), no window register cache, no logit arrays
//  - streaming no-max exp2 softmax: s,o accumulated as window cols are read
//  - weights/emb via uniform scalar loads (SGPRs), one __syncthreads
//  - XCD swizzle bijective (8192 = 8*1024), chunk id fastest-varying so the
//    4 blocks sharing an x tile are adjacent on one XCD (L2 reuse)

#define HH 128
#define WW 128
#define HW (HH * WW)
#define PW 34          // padded tile width  (32 + halo)
#define PH 18          // padded tile height (16 + halo)
#define PWP 35         // padded row stride
#define LOG2E 1.44269504088896f

__global__ __launch_bounds__(256, 8) void sab_fused(
    const float* __restrict__ x,
    const float* __restrict__ Wq,
    const float* __restrict__ Wk,
    const float* __restrict__ Wv,
    const float* __restrict__ h_emb,
    const float* __restrict__ w_emb,
    float* __restrict__ out)
{
    __shared__ float2 kv[2][PH][PWP];   // [cc][row][col], .x=k .y=v  (9.9 KB)

    const int bid0 = blockIdx.x;
    const int work = (bid0 & 7) * 1024 + (bid0 >> 3);   // bijective XCD swizzle
    const int c0   = (work & 3) << 1;          // channel chunk: {0,2,4,6}
    const int tile = (work >> 2) & 31;         // 4 cols x 8 rows of 32x16 tiles
    const int bg   = work >> 7;                // b*8 + g
    const int g    = bg & 7;
    const int h0   = (tile >> 2) << 4;
    const int w0   = (tile & 3) << 5;
    const int tid  = threadIdx.x;
    const int ry   = tid >> 4;                 // 0..15
    const int cx   = (tid & 15) << 1;          // 0,2,..,30

    const float* xb = x + (size_t)bg * 8 * HW;

    // ---- interior x: 2 px, 8 channels (dwordx2) ----
    const int ibase = (h0 + ry) * WW + (w0 + cx);
    float2 xi[8];
    #pragma unroll
    for (int i = 0; i < 8; i++)
        xi[i] = *reinterpret_cast<const float2*>(xb + i * HW + ibase);

    // ---- halo x: 100 perimeter px on threads 0..99 ----
    float hx[8];
    int hpy = 0, hpx = 0;
    const bool is_halo = tid < 100;
    if (is_halo) {
        if (tid < 34)      { hpy = 0;        hpx = tid; }
        else if (tid < 68) { hpy = 17;       hpx = tid - 34; }
        else if (tid < 84) { hpy = tid - 67; hpx = 0; }    // rows 1..16
        else               { hpy = tid - 83; hpx = 33; }
        const int gh = h0 + hpy - 1, gw = w0 + hpx - 1;
        const bool ok = (gh >= 0) & (gh < HH) & (gw >= 0) & (gw < WW);
        const int base = gh * WW + gw;
        #pragma unroll
        for (int i = 0; i < 8; i++)
            hx[i] = ok ? xb[i * HW + base] : 0.0f;
    }

    // ---- uniform weight + emb loads (block-uniform -> SGPR) ----
    float wk[2][8], wv[2][8], wq[2][8], eb[2][9];
    #pragma unroll
    for (int cc = 0; cc < 2; cc++) {
        const int c = c0 + cc;
        #pragma unroll
        for (int i = 0; i < 8; i++) {
            wk[cc][i] = Wk[g * 64 + c * 8 + i];
            wv[cc][i] = Wv[g * 64 + c * 8 + i];
            wq[cc][i] = Wq[g * 64 + c * 8 + i];
        }
        #pragma unroll
        for (int p = 0; p < 9; p++) {
            // channels 0-3: h_emb (ki = p/3); 4-7: w_emb (kj = p%3)
            eb[cc][p] = (c < 4) ? h_emb[(g * 4 + c) * 3 + p / 3]
                                : w_emb[(g * 4 + c - 4) * 3 + p % 3];
        }
    }

    // ---- conv: k,v -> LDS, q (exp2-domain) -> regs ----
    float q[2][2];
    #pragma unroll
    for (int cc = 0; cc < 2; cc++) {
        #pragma unroll
        for (int px = 0; px < 2; px++) {
            float kk = 0.f, vv = 0.f, qq = 0.f;
            #pragma unroll
            for (int i = 0; i < 8; i++) {
                const float xs = px ? xi[i].y : xi[i].x;
                kk = fmaf(wk[cc][i], xs, kk);
                vv = fmaf(wv[cc][i], xs, vv);
                qq = fmaf(wq[cc][i], xs, qq);
            }
            kv[cc][ry + 1][cx + 1 + px] = make_float2(kk, vv);
            q[cc][px] = qq * LOG2E;
        }
        if (is_halo) {
            float hk = 0.f, hv = 0.f;
            #pragma unroll
            for (int i = 0; i < 8; i++) {
                hk = fmaf(wk[cc][i], hx[i], hk);
                hv = fmaf(wv[cc][i], hx[i], hv);
            }
            kv[cc][hpy][hpx] = make_float2(hk, hv);
        }
    }
    __syncthreads();

    // ---- attention: streaming no-max softmax over the 3x3 window ----
    float s[2][2] = {{0.f, 0.f}, {0.f, 0.f}};
    float o[2][2] = {{0.f, 0.f}, {0.f, 0.f}};
    #pragma unroll
    for (int dh = 0; dh < 3; dh++) {
        #pragma unroll
        for (int cc = 0; cc < 2; cc++) {
            const float2 a0 = kv[cc][ry + dh][cx + 0];
            const float2 a1 = kv[cc][ry + dh][cx + 1];
            const float2 a2 = kv[cc][ry + dh][cx + 2];
            const float2 a3 = kv[cc][ry + dh][cx + 3];
            const float2 w4[4] = {a0, a1, a2, a3};
            #pragma unroll
            for (int dw = 0; dw < 3; dw++) {
                const float ebv = eb[cc][dh * 3 + dw];
                const float e0 = __builtin_amdgcn_exp2f(q[cc][0] * (w4[dw].x + ebv));
                s[cc][0] += e0;
                o[cc][0] = fmaf(e0, w4[dw].y, o[cc][0]);
                const float e1 = __builtin_amdgcn_exp2f(q[cc][1] * (w4[dw + 1].x + ebv));
                s[cc][1] += e1;
                o[cc][1] = fmaf(e1, w4[dw + 1].y, o[cc][1]);
            }
        }
    }

    // ---- store (dwordx2 per channel) ----
    #pragma unroll
    for (int cc = 0; cc < 2; cc++) {
        float2 r;
        r.x = o[cc][0] * __builtin_amdgcn_rcpf(s[cc][0]);
        r.y = o[cc][1] * __builtin_amdgcn_rcpf(s[cc][1]);
        *reinterpret_cast<float2*>(out + (size_t)(bg * 8 + c0 + cc) * HW + ibase) = r;
    }
}

extern "C" void kernel_launch(void* const* d_in, const int* in_sizes, int n_in,
                              void* d_out, int out_size, void* d_ws, size_t ws_size,
                              hipStream_t stream) {
    const float* x    = (const float*)d_in[0];
    const float* Wq   = (const float*)d_in[1];
    const float* Wk   = (const float*)d_in[2];
    const float* Wv   = (const float*)d_in[3];
    const float* h_e  = (const float*)d_in[4];
    const float* w_e  = (const float*)d_in[5];
    float* out = (float*)d_out;

    dim3 grid(8 * 8 * 32 * 4);   // (b,g) x 32 tiles x 4 channel-chunks = 8192
    dim3 block(256);
    sab_fused<<<grid, block, 0, stream>>>(x, Wq, Wk, Wv, h_e, w_e, out);
}

// Round 7
// 32.695 us; speedup vs baseline: 1.4025x; 1.4025x over previous
//
#include <hip/hip_runtime.h>

// Stand-alone self-attention block, fully fused.
// x:(8,64,128,128) f32 -> out same shape. G=8, Cg=8, 3x3 window, pad 1.
//
// R7 = R6 (32x16 tile x 2-ch chunk, 2 px/thread, streaming no-max exp2
// softmax, 8 waves/EU target) + spill fix:
//  - ALL 66 weight/emb values forced into SGPRs via readfirstlane
//    (block-uniform, so exact). R6 kept them in VGPRs -> 66-reg overflow
//    -> scratch spills (WRITE_SIZE 99 MB vs 33.5 MB logical).
//  - halo x is transient inside the halo branch (no long-lived hx[8]).
// Target: true VGPR <= 64 (8 waves/EU = 32 waves/CU), zero scratch.

#define HH 128
#define WW 128
#define HW (HH * WW)
#define PH 18          // padded tile height (16 + halo)
#define PWP 35         // padded row stride (34 + 1)
#define LOG2E 1.44269504088896f

__device__ __forceinline__ float sload(float v) {
    // force block-uniform value into an SGPR
    return __uint_as_float(__builtin_amdgcn_readfirstlane(__float_as_uint(v)));
}

__global__ __launch_bounds__(256, 8) void sab_fused(
    const float* __restrict__ x,
    const float* __restrict__ Wq,
    const float* __restrict__ Wk,
    const float* __restrict__ Wv,
    const float* __restrict__ h_emb,
    const float* __restrict__ w_emb,
    float* __restrict__ out)
{
    __shared__ float2 kv[2][PH][PWP];   // [cc][row][col], .x=k .y=v  (9.9 KB)

    const int bid0 = blockIdx.x;
    const int work = (bid0 & 7) * 1024 + (bid0 >> 3);   // bijective XCD swizzle
    const int c0   = (work & 3) << 1;          // channel chunk: {0,2,4,6}
    const int tile = (work >> 2) & 31;         // 4 cols x 8 rows of 32x16 tiles
    const int bg   = work >> 7;                // b*8 + g
    const int g    = bg & 7;
    const int h0   = (tile >> 2) << 4;
    const int w0   = (tile & 3) << 5;
    const int tid  = threadIdx.x;
    const int ry   = tid >> 4;                 // 0..15
    const int cx   = (tid & 15) << 1;          // 0,2,..,30

    // ---- weights + emb -> SGPRs (readfirstlane-forced) ----
    float wk[2][8], wv[2][8], wq[2][8], eb[2][9];
    #pragma unroll
    for (int cc = 0; cc < 2; cc++) {
        const int c = c0 + cc;
        #pragma unroll
        for (int i = 0; i < 8; i++) {
            wk[cc][i] = sload(Wk[g * 64 + c * 8 + i]);
            wv[cc][i] = sload(Wv[g * 64 + c * 8 + i]);
            wq[cc][i] = sload(Wq[g * 64 + c * 8 + i]);
        }
        #pragma unroll
        for (int p = 0; p < 9; p++) {
            // channels 0-3: h_emb (ki = p/3); 4-7: w_emb (kj = p%3)
            eb[cc][p] = sload((c < 4) ? h_emb[(g * 4 + c) * 3 + p / 3]
                                      : w_emb[(g * 4 + c - 4) * 3 + p % 3]);
        }
    }

    const float* xb = x + (size_t)bg * 8 * HW;
    const int ibase = (h0 + ry) * WW + (w0 + cx);

    // ---- interior x: 2 px, 8 channels (dwordx2) ----
    float2 xi[8];
    #pragma unroll
    for (int i = 0; i < 8; i++)
        xi[i] = *reinterpret_cast<const float2*>(xb + i * HW + ibase);

    // ---- conv: k,v -> LDS, q (exp2-domain) -> regs ----
    float q[2][2];
    #pragma unroll
    for (int cc = 0; cc < 2; cc++) {
        #pragma unroll
        for (int px = 0; px < 2; px++) {
            float kk = 0.f, vv = 0.f, qq = 0.f;
            #pragma unroll
            for (int i = 0; i < 8; i++) {
                const float xs = px ? xi[i].y : xi[i].x;
                kk = fmaf(wk[cc][i], xs, kk);
                vv = fmaf(wv[cc][i], xs, vv);
                qq = fmaf(wq[cc][i], xs, qq);
            }
            kv[cc][ry + 1][cx + 1 + px] = make_float2(kk, vv);
            q[cc][px] = qq * LOG2E;
        }
    }

    // ---- halo: 100 perimeter px on threads 0..99 (all state transient) ----
    if (tid < 100) {
        int hpy, hpx;
        if (tid < 34)      { hpy = 0;        hpx = tid; }
        else if (tid < 68) { hpy = 17;       hpx = tid - 34; }
        else if (tid < 84) { hpy = tid - 67; hpx = 0; }    // rows 1..16
        else               { hpy = tid - 83; hpx = 33; }
        const int gh = h0 + hpy - 1, gw = w0 + hpx - 1;
        const bool ok = (gh >= 0) & (gh < HH) & (gw >= 0) & (gw < WW);
        const int base = gh * WW + gw;
        float hk0 = 0.f, hv0 = 0.f, hk1 = 0.f, hv1 = 0.f;
        #pragma unroll
        for (int i = 0; i < 8; i++) {
            const float xv = ok ? xb[i * HW + base] : 0.0f;
            hk0 = fmaf(wk[0][i], xv, hk0);
            hv0 = fmaf(wv[0][i], xv, hv0);
            hk1 = fmaf(wk[1][i], xv, hk1);
            hv1 = fmaf(wv[1][i], xv, hv1);
        }
        kv[0][hpy][hpx] = make_float2(hk0, hv0);
        kv[1][hpy][hpx] = make_float2(hk1, hv1);
    }
    __syncthreads();

    // ---- attention: streaming no-max softmax over the 3x3 window ----
    float s[2][2] = {{0.f, 0.f}, {0.f, 0.f}};
    float o[2][2] = {{0.f, 0.f}, {0.f, 0.f}};
    #pragma unroll
    for (int dh = 0; dh < 3; dh++) {
        #pragma unroll
        for (int cc = 0; cc < 2; cc++) {
            const float2 a0 = kv[cc][ry + dh][cx + 0];
            const float2 a1 = kv[cc][ry + dh][cx + 1];
            const float2 a2 = kv[cc][ry + dh][cx + 2];
            const float2 a3 = kv[cc][ry + dh][cx + 3];
            const float2 w4[4] = {a0, a1, a2, a3};
            #pragma unroll
            for (int dw = 0; dw < 3; dw++) {
                const float ebv = eb[cc][dh * 3 + dw];
                const float e0 = __builtin_amdgcn_exp2f(q[cc][0] * (w4[dw].x + ebv));
                s[cc][0] += e0;
                o[cc][0] = fmaf(e0, w4[dw].y, o[cc][0]);
                const float e1 = __builtin_amdgcn_exp2f(q[cc][1] * (w4[dw + 1].x + ebv));
                s[cc][1] += e1;
                o[cc][1] = fmaf(e1, w4[dw + 1].y, o[cc][1]);
            }
        }
    }

    // ---- store (dwordx2 per channel) ----
    #pragma unroll
    for (int cc = 0; cc < 2; cc++) {
        float2 r;
        r.x = o[cc][0] * __builtin_amdgcn_rcpf(s[cc][0]);
        r.y = o[cc][1] * __builtin_amdgcn_rcpf(s[cc][1]);
        *reinterpret_cast<float2*>(out + (size_t)(bg * 8 + c0 + cc) * HW + ibase) = r;
    }
}

extern "C" void kernel_launch(void* const* d_in, const int* in_sizes, int n_in,
                              void* d_out, int out_size, void* d_ws, size_t ws_size,
                              hipStream_t stream) {
    const float* x    = (const float*)d_in[0];
    const float* Wq   = (const float*)d_in[1];
    const float* Wk   = (const float*)d_in[2];
    const float* Wv   = (const float*)d_in[3];
    const float* h_e  = (const float*)d_in[4];
    const float* w_e  = (const float*)d_in[5];
    float* out = (float*)d_out;

    dim3 grid(8 * 8 * 32 * 4);   // (b,g) x 32 tiles x 4 channel-chunks = 8192
    dim3 block(256);
    sab_fused<<<grid, block, 0, stream>>>(x, Wq, Wk, Wv, h_e, w_e, out);
}

// Round 8
// 28.753 us; speedup vs baseline: 1.5948x; 1.1371x over previous
//
#include <hip/hip_runtime.h>

// Stand-alone self-attention block, fully fused.
// x:(8,64,128,128) f32 -> out same shape. G=8, Cg=8, 3x3 window, pad 1.
//
// R8 = R5 structure (best: 32x32 tile x 2-ch chunk, 4 px/thread, 4096
// blocks) + instruction-count attack:
//  - packed f32 math via ext_vector_type(4): conv + softmax arithmetic
//    compile to v_pk_fma_f32 / v_pk_mul_f32 / v_pk_add_f32 (2x VALU density)
//  - kv interleaved float2 LDS with row stride 38: b128 reads, bank groups
//    (3r+2j+c)%8 spread perfectly even -> conflict-free reads; 18 b128
//    reads/thread replace 36 b64
//  - weights/emb readfirstlane-forced into SGPRs (R7-proven, no spill)
//  - streaming softmax rows (no 3-row register cache), exp2-domain no-max,
//    v_rcp normalize

typedef float v2f __attribute__((ext_vector_type(2)));
typedef float v4f __attribute__((ext_vector_type(4)));

#define HH 128
#define WW 128
#define HW (HH * WW)
#define PT 34          // padded tile extent (32 + halo)
#define PTS 38         // row stride in float2 (34 + 4 pad; 38*8 B % 16 == 0)
#define LOG2E 1.44269504088896f

__device__ __forceinline__ float sload(float v) {
    // force block-uniform value into an SGPR
    return __uint_as_float(__builtin_amdgcn_readfirstlane(__float_as_uint(v)));
}

__device__ __forceinline__ v4f exp2v4(v4f a) {
    v4f r;
    r.x = __builtin_amdgcn_exp2f(a.x);
    r.y = __builtin_amdgcn_exp2f(a.y);
    r.z = __builtin_amdgcn_exp2f(a.z);
    r.w = __builtin_amdgcn_exp2f(a.w);
    return r;
}

__global__ __launch_bounds__(256) void sab_fused(
    const float* __restrict__ x,
    const float* __restrict__ Wq,
    const float* __restrict__ Wk,
    const float* __restrict__ Wv,
    const float* __restrict__ h_emb,
    const float* __restrict__ w_emb,
    float* __restrict__ out)
{
    __shared__ v2f kv[2][PT][PTS];      // [cc][row][col] {k,v}  (20.7 KB)

    const int bid0 = blockIdx.x;
    const int work = (bid0 & 7) * 512 + (bid0 >> 3);   // bijective XCD swizzle
    const int c0   = (work & 3) << 1;          // channel chunk {0,2,4,6}
    const int tile = (work >> 2) & 15;         // 4x4 tiles of 32x32
    const int bg   = work >> 6;                // b*8 + g
    const int g    = bg & 7;
    const int h0   = (tile >> 2) << 5;
    const int w0   = (tile & 3) << 5;
    const int tid  = threadIdx.x;
    const int ty   = tid >> 3;                 // 0..31
    const int x0   = (tid & 7) << 2;           // 0,4,..,28

    // ---- weights + emb -> SGPRs (readfirstlane-forced) ----
    float wk[2][8], wv[2][8], wq[2][8], eb[2][9];
    #pragma unroll
    for (int cc = 0; cc < 2; cc++) {
        const int c = c0 + cc;
        #pragma unroll
        for (int i = 0; i < 8; i++) {
            wk[cc][i] = sload(Wk[g * 64 + c * 8 + i]);
            wv[cc][i] = sload(Wv[g * 64 + c * 8 + i]);
            wq[cc][i] = sload(Wq[g * 64 + c * 8 + i]);
        }
        #pragma unroll
        for (int p = 0; p < 9; p++) {
            // channels 0-3: h_emb (ki = p/3); 4-7: w_emb (kj = p%3)
            eb[cc][p] = sload((c < 4) ? h_emb[(g * 4 + c) * 3 + p / 3]
                                      : w_emb[(g * 4 + c - 4) * 3 + p % 3]);
        }
    }

    const float* xb = x + (size_t)bg * 8 * HW;
    const int ibase = (h0 + ty) * WW + (w0 + x0);

    // ---- interior x: 4 px, 8 channels (dwordx4) ----
    v4f xi[8];
    #pragma unroll
    for (int i = 0; i < 8; i++)
        xi[i] = *reinterpret_cast<const v4f*>(xb + i * HW + ibase);

    // ---- conv (packed): k,v -> LDS, q -> regs ----
    v4f kk0 = 0.f, vv0 = 0.f, qq0 = 0.f, kk1 = 0.f, vv1 = 0.f, qq1 = 0.f;
    #pragma unroll
    for (int i = 0; i < 8; i++) {
        const v4f xv = xi[i];
        kk0 += wk[0][i] * xv;  vv0 += wv[0][i] * xv;  qq0 += wq[0][i] * xv;
        kk1 += wk[1][i] * xv;  vv1 += wv[1][i] * xv;  qq1 += wq[1][i] * xv;
    }
    #pragma unroll
    for (int px = 0; px < 4; px++) {
        kv[0][ty + 1][x0 + 1 + px] = (v2f){kk0[px], vv0[px]};
        kv[1][ty + 1][x0 + 1 + px] = (v2f){kk1[px], vv1[px]};
    }
    const v4f q0 = qq0 * LOG2E;
    const v4f q1 = qq1 * LOG2E;

    // ---- halo: 132 perimeter px on threads 0..131 (transient state) ----
    if (tid < 132) {
        int hpy, hpx;
        if (tid < 34)       { hpy = 0;        hpx = tid; }
        else if (tid < 68)  { hpy = 33;       hpx = tid - 34; }
        else if (tid < 100) { hpy = tid - 67; hpx = 0; }     // rows 1..32
        else                { hpy = tid - 99; hpx = 33; }
        const int gh = h0 + hpy - 1, gw = w0 + hpx - 1;
        const bool ok = (gh >= 0) & (gh < HH) & (gw >= 0) & (gw < WW);
        const int base = gh * WW + gw;
        float hk0 = 0.f, hv0 = 0.f, hk1 = 0.f, hv1 = 0.f;
        #pragma unroll
        for (int i = 0; i < 8; i++) {
            const float xv = ok ? xb[i * HW + base] : 0.0f;
            hk0 = fmaf(wk[0][i], xv, hk0);
            hv0 = fmaf(wv[0][i], xv, hv0);
            hk1 = fmaf(wk[1][i], xv, hk1);
            hv1 = fmaf(wv[1][i], xv, hv1);
        }
        kv[0][hpy][hpx] = (v2f){hk0, hv0};
        kv[1][hpy][hpx] = (v2f){hk1, hv1};
    }
    __syncthreads();

    // ---- attention: streaming rows, packed 4-px softmax ----
    v4f s0 = 0.f, o0 = 0.f, s1 = 0.f, o1 = 0.f;
    #pragma unroll
    for (int dh = 0; dh < 3; dh++) {
        #pragma unroll
        for (int cc = 0; cc < 2; cc++) {
            const v2f* row = &kv[cc][ty + dh][x0];
            const v4f a = *reinterpret_cast<const v4f*>(row);       // k0 v0 k1 v1
            const v4f bq = *reinterpret_cast<const v4f*>(row + 2);  // k2 v2 k3 v3
            const v4f cq = *reinterpret_cast<const v4f*>(row + 4);  // k4 v4 k5 v5

            const v4f kd0 = {a.x, a.z, bq.x, bq.z};
            const v4f vd0 = {a.y, a.w, bq.y, bq.w};
            const v4f kd1 = {a.z, bq.x, bq.z, cq.x};
            const v4f vd1 = {a.w, bq.y, bq.w, cq.y};
            const v4f kd2 = {bq.x, bq.z, cq.x, cq.z};
            const v4f vd2 = {bq.y, bq.w, cq.y, cq.w};

            const v4f q4 = cc ? q1 : q0;
            v4f e;
            e = exp2v4(q4 * (kd0 + eb[cc][dh * 3 + 0]));
            if (cc) { s1 += e; o1 += e * vd0; } else { s0 += e; o0 += e * vd0; }
            e = exp2v4(q4 * (kd1 + eb[cc][dh * 3 + 1]));
            if (cc) { s1 += e; o1 += e * vd1; } else { s0 += e; o0 += e * vd1; }
            e = exp2v4(q4 * (kd2 + eb[cc][dh * 3 + 2]));
            if (cc) { s1 += e; o1 += e * vd2; } else { s0 += e; o0 += e * vd2; }
        }
    }

    // ---- normalize + store (dwordx4 per channel) ----
    v4f r0, r1;
    #pragma unroll
    for (int px = 0; px < 4; px++) {
        r0[px] = o0[px] * __builtin_amdgcn_rcpf(s0[px]);
        r1[px] = o1[px] * __builtin_amdgcn_rcpf(s1[px]);
    }
    *reinterpret_cast<v4f*>(out + (size_t)(bg * 8 + c0 + 0) * HW + ibase) = r0;
    *reinterpret_cast<v4f*>(out + (size_t)(bg * 8 + c0 + 1) * HW + ibase) = r1;
}

extern "C" void kernel_launch(void* const* d_in, const int* in_sizes, int n_in,
                              void* d_out, int out_size, void* d_ws, size_t ws_size,
                              hipStream_t stream) {
    const float* x    = (const float*)d_in[0];
    const float* Wq   = (const float*)d_in[1];
    const float* Wk   = (const float*)d_in[2];
    const float* Wv   = (const float*)d_in[3];
    const float* h_e  = (const float*)d_in[4];
    const float* w_e  = (const float*)d_in[5];
    float* out = (float*)d_out;

    dim3 grid(8 * 8 * 16 * 4);   // (b,g) x 4x4 tiles x 4 channel-chunks
    dim3 block(256);
    sab_fused<<<grid, block, 0, stream>>>(x, Wq, Wk, Wv, h_e, w_e, out);
}